// Round 3
// baseline (2326.836 us; speedup 1.0000x reference)
//
#include <hip/hip_runtime.h>

// Problem constants (from reference setup_inputs)
#define BB 4
#define MM 16384
#define NN 32768
#define KK 16
#define ROWS (BB * NN)   // 131072
#define OUTW 131         // 3 coords + 64 + 64
#define RPW 32           // rows per wave
#define NPASS 8          // 4 rows per pass
#define GRID_N 1024      // 4 blocks/CU exact (barrier-safe: VGPR<=128, LDS 21KB)
#define PSTR 68          // padded x-tile stride in words (68%32=4 -> rg spread, conflict-free)

// ws layout: [0:64] sum1 [64:128] sq1 [128:192] sum2 [192:256] sq2
//            int counters at ((int*)ws)[256] (kernel A) and [257] (kernel B)

__device__ __forceinline__ void fma4(float4& a, float s, float4 w) {
    a.x = fmaf(s, w.x, a.x); a.y = fmaf(s, w.y, a.y);
    a.z = fmaf(s, w.z, a.z); a.w = fmaf(s, w.w, a.w);
}

// Software grid barrier. Safe: grid == 1024 == 4 blocks/CU * 256 CUs, and
// VGPR cap 128 (waves_per_eu(4,4)) + LDS 21KB guarantee >=4 blocks/CU capacity,
// so all 1024 blocks are co-resident. Validated in round 1 (passed, no hang).
__device__ __forceinline__ void grid_barrier(int* bar, int nblk) {
    __threadfence();
    __syncthreads();
    if (threadIdx.x == 0) {
        __hip_atomic_fetch_add(bar, 1, __ATOMIC_ACQ_REL, __HIP_MEMORY_SCOPE_AGENT);
        while (__hip_atomic_load(bar, __ATOMIC_ACQUIRE, __HIP_MEMORY_SCOPE_AGENT) < nblk)
            __builtin_amdgcn_s_sleep(8);
    }
    __syncthreads();
}

// ---------------------------------------------------------------------------
// Kernel A: gather + max-pool + proj + stats + grid-sync + BN/ReLU writeout.
// Gather phase: lane = channel (coalesced 256B cf lines), idx via readlane->SGPR.
// Compute phase: lane = (cg,rg): 4 channels x 4 rows, x broadcast from padded
// LDS tile, W from LDS b128 -> weight traffic amortized 4x per read.
// All loops fully unrolled; no array exceeds 8 elems; static indices only
// (round-2 lesson: runtime-indexed arrays -> scratch -> 1GB HBM thrash).
// ---------------------------------------------------------------------------
__global__ __launch_bounds__(256) __attribute__((amdgpu_waves_per_eu(4, 4)))
void k_pool_proj(
    const float* __restrict__ cf, const int* __restrict__ idxs,
    const float* __restrict__ scoord,
    const float* __restrict__ W1, const float* __restrict__ b1,
    const float* __restrict__ g1, const float* __restrict__ be1,
    float* __restrict__ out, float* __restrict__ ws)
{
    __shared__ float Wl[4096];            // 64x64 W tile, 16 KB
    __shared__ float xT[4 * 4 * PSTR];    // per-wave 4-row x tile, padded
    __shared__ float lsum[64], lsq[64];

    const int tid  = threadIdx.x;
    const int lane = tid & 63;
    const int wv   = tid >> 6;
    const int cg   = lane & 15;
    const int rg   = lane >> 4;
    const int ch   = cg * 4;

    {   // stage W1 -> LDS (1024 float4, 4 per thread)
        const float4* Wg = (const float4*)W1;
        float4* Wd = (float4*)Wl;
#pragma unroll
        for (int i = 0; i < 4; ++i) Wd[tid + i * 256] = Wg[tid + i * 256];
    }
    if (tid < 64) { lsum[tid] = 0.f; lsq[tid] = 0.f; }
    __syncthreads();

    // XCD swizzle (validated r1: FETCH 211->45 MB): block w -> XCD w&7;
    // each batch owns 2 XCDs so its 4.2 MB cf slice stays L2-resident.
    const int w     = blockIdx.x;
    const int xcd   = w & 7;
    const int batch = xcd >> 1;
    const int lb    = (w >> 3) + ((xcd & 1) << 7);   // [0,256) within batch
    const int rbase = batch * NN + (lb * 4 + wv) * RPW;
    const float* cfb = cf + ((size_t)batch << 20);

    const float4 bias4 = *(const float4*)(b1 + ch);
    const int wvb = wv * (4 * PSTR);

    float4 ysv[NPASS];
    float4 ps = make_float4(0.f, 0.f, 0.f, 0.f);
    float4 pq = make_float4(0.f, 0.f, 0.f, 0.f);

#pragma unroll
    for (int p = 0; p < NPASS; ++p) {
        const int r4 = rbase + p * 4;
        // 4 rows x 16 indices in one full-wave coalesced load
        const int mi = idxs[(size_t)r4 * KK + lane];
        float pm[4];
#pragma unroll
        for (int rr = 0; rr < 4; ++rr) {
            float a0 = -3.402823466e38f, a1 = a0;
#pragma unroll
            for (int k = 0; k < KK; k += 2) {
                const int m0 = __builtin_amdgcn_readlane(mi, rr * 16 + k);
                const int m1 = __builtin_amdgcn_readlane(mi, rr * 16 + k + 1);
                a0 = fmaxf(a0, cfb[((size_t)m0 << 6) + lane]);
                a1 = fmaxf(a1, cfb[((size_t)m1 << 6) + lane]);
            }
            pm[rr] = fmaxf(a0, a1);
        }
        if (lane < 12) {   // coords for these 4 rows
            const int rr = lane / 3, cc = lane - rr * 3;
            out[(size_t)(r4 + rr) * OUTW + cc] = scoord[(size_t)(r4 + rr) * 3 + cc];
        }
#pragma unroll
        for (int rr = 0; rr < 4; ++rr) xT[wvb + rr * PSTR + lane] = pm[rr];
        __builtin_amdgcn_wave_barrier();

        float4 acc = bias4;
#pragma unroll
        for (int c4 = 0; c4 < 16; ++c4) {
            const float4 xv = *(const float4*)&xT[wvb + rg * PSTR + c4 * 4];
            const float4 w0 = *(const float4*)&Wl[(c4 * 4 + 0) * 64 + ch];
            const float4 w1 = *(const float4*)&Wl[(c4 * 4 + 1) * 64 + ch];
            const float4 w2 = *(const float4*)&Wl[(c4 * 4 + 2) * 64 + ch];
            const float4 w3 = *(const float4*)&Wl[(c4 * 4 + 3) * 64 + ch];
            fma4(acc, xv.x, w0); fma4(acc, xv.y, w1);
            fma4(acc, xv.z, w2); fma4(acc, xv.w, w3);
        }
        __builtin_amdgcn_wave_barrier();
        ysv[p] = acc;
        ps.x += acc.x; ps.y += acc.y; ps.z += acc.z; ps.w += acc.w;
        pq.x += acc.x * acc.x; pq.y += acc.y * acc.y;
        pq.z += acc.z * acc.z; pq.w += acc.w * acc.w;
    }

    // reduce stats over the 4 rg groups (lanes xor 16, 32), then LDS+global
#pragma unroll
    for (int m = 16; m <= 32; m <<= 1) {
        ps.x += __shfl_xor(ps.x, m); ps.y += __shfl_xor(ps.y, m);
        ps.z += __shfl_xor(ps.z, m); ps.w += __shfl_xor(ps.w, m);
        pq.x += __shfl_xor(pq.x, m); pq.y += __shfl_xor(pq.y, m);
        pq.z += __shfl_xor(pq.z, m); pq.w += __shfl_xor(pq.w, m);
    }
    if (rg == 0) {
        atomicAdd(&lsum[ch + 0], ps.x); atomicAdd(&lsum[ch + 1], ps.y);
        atomicAdd(&lsum[ch + 2], ps.z); atomicAdd(&lsum[ch + 3], ps.w);
        atomicAdd(&lsq[ch + 0], pq.x);  atomicAdd(&lsq[ch + 1], pq.y);
        atomicAdd(&lsq[ch + 2], pq.z);  atomicAdd(&lsq[ch + 3], pq.w);
    }
    __syncthreads();
    if (tid < 64) {
        atomicAdd(&ws[tid],      lsum[tid]);
        atomicAdd(&ws[64 + tid], lsq[tid]);
    }

    grid_barrier((int*)ws + 256, GRID_N);

    const float inv = 1.0f / (float)ROWS;
    float a4[4], c4v[4];
#pragma unroll
    for (int j = 0; j < 4; ++j) {
        const float s = __hip_atomic_load(&ws[ch + j],      __ATOMIC_RELAXED, __HIP_MEMORY_SCOPE_AGENT);
        const float q = __hip_atomic_load(&ws[64 + ch + j], __ATOMIC_RELAXED, __HIP_MEMORY_SCOPE_AGENT);
        const float m = s * inv;
        const float v = q * inv - m * m;
        const float a = g1[ch + j] * rsqrtf(v + 1e-5f);
        a4[j] = a; c4v[j] = be1[ch + j] - m * a;
    }
#pragma unroll
    for (int p = 0; p < NPASS; ++p) {
        const size_t base = (size_t)(rbase + p * 4 + rg) * OUTW + 3 + ch;
        out[base + 0] = fmaxf(fmaf(ysv[p].x, a4[0], c4v[0]), 0.f);
        out[base + 1] = fmaxf(fmaf(ysv[p].y, a4[1], c4v[1]), 0.f);
        out[base + 2] = fmaxf(fmaf(ysv[p].z, a4[2], c4v[2]), 0.f);
        out[base + 3] = fmaxf(fmaf(ysv[p].w, a4[3], c4v[3]), 0.f);
    }
}

// ---------------------------------------------------------------------------
// Kernel B: skip_feat proj + stats + grid-sync + BN/ReLU -> out[..., 67:131]
// Same structure; x comes from 4 coalesced sf loads instead of the gather.
// ---------------------------------------------------------------------------
__global__ __launch_bounds__(256) __attribute__((amdgpu_waves_per_eu(4, 4)))
void k_skip_proj(
    const float* __restrict__ sf,
    const float* __restrict__ W2, const float* __restrict__ b2,
    const float* __restrict__ g2, const float* __restrict__ be2,
    float* __restrict__ out, float* __restrict__ ws)
{
    __shared__ float Wl[4096];
    __shared__ float xT[4 * 4 * PSTR];
    __shared__ float lsum[64], lsq[64];

    const int tid  = threadIdx.x;
    const int lane = tid & 63;
    const int wv   = tid >> 6;
    const int cg   = lane & 15;
    const int rg   = lane >> 4;
    const int ch   = cg * 4;

    {
        const float4* Wg = (const float4*)W2;
        float4* Wd = (float4*)Wl;
#pragma unroll
        for (int i = 0; i < 4; ++i) Wd[tid + i * 256] = Wg[tid + i * 256];
    }
    if (tid < 64) { lsum[tid] = 0.f; lsq[tid] = 0.f; }
    __syncthreads();

    const int rbase = (blockIdx.x * 4 + wv) * RPW;
    const float4 bias4 = *(const float4*)(b2 + ch);
    const int wvb = wv * (4 * PSTR);

    float4 ysv[NPASS];
    float4 ps = make_float4(0.f, 0.f, 0.f, 0.f);
    float4 pq = make_float4(0.f, 0.f, 0.f, 0.f);

#pragma unroll
    for (int p = 0; p < NPASS; ++p) {
        const int r4 = rbase + p * 4;
#pragma unroll
        for (int rr = 0; rr < 4; ++rr)
            xT[wvb + rr * PSTR + lane] = sf[(size_t)(r4 + rr) * 64 + lane];
        __builtin_amdgcn_wave_barrier();

        float4 acc = bias4;
#pragma unroll
        for (int c4 = 0; c4 < 16; ++c4) {
            const float4 xv = *(const float4*)&xT[wvb + rg * PSTR + c4 * 4];
            const float4 w0 = *(const float4*)&Wl[(c4 * 4 + 0) * 64 + ch];
            const float4 w1 = *(const float4*)&Wl[(c4 * 4 + 1) * 64 + ch];
            const float4 w2 = *(const float4*)&Wl[(c4 * 4 + 2) * 64 + ch];
            const float4 w3 = *(const float4*)&Wl[(c4 * 4 + 3) * 64 + ch];
            fma4(acc, xv.x, w0); fma4(acc, xv.y, w1);
            fma4(acc, xv.z, w2); fma4(acc, xv.w, w3);
        }
        __builtin_amdgcn_wave_barrier();
        ysv[p] = acc;
        ps.x += acc.x; ps.y += acc.y; ps.z += acc.z; ps.w += acc.w;
        pq.x += acc.x * acc.x; pq.y += acc.y * acc.y;
        pq.z += acc.z * acc.z; pq.w += acc.w * acc.w;
    }

#pragma unroll
    for (int m = 16; m <= 32; m <<= 1) {
        ps.x += __shfl_xor(ps.x, m); ps.y += __shfl_xor(ps.y, m);
        ps.z += __shfl_xor(ps.z, m); ps.w += __shfl_xor(ps.w, m);
        pq.x += __shfl_xor(pq.x, m); pq.y += __shfl_xor(pq.y, m);
        pq.z += __shfl_xor(pq.z, m); pq.w += __shfl_xor(pq.w, m);
    }
    if (rg == 0) {
        atomicAdd(&lsum[ch + 0], ps.x); atomicAdd(&lsum[ch + 1], ps.y);
        atomicAdd(&lsum[ch + 2], ps.z); atomicAdd(&lsum[ch + 3], ps.w);
        atomicAdd(&lsq[ch + 0], pq.x);  atomicAdd(&lsq[ch + 1], pq.y);
        atomicAdd(&lsq[ch + 2], pq.z);  atomicAdd(&lsq[ch + 3], pq.w);
    }
    __syncthreads();
    if (tid < 64) {
        atomicAdd(&ws[128 + tid], lsum[tid]);
        atomicAdd(&ws[192 + tid], lsq[tid]);
    }

    grid_barrier((int*)ws + 257, GRID_N);

    const float inv = 1.0f / (float)ROWS;
    float a4[4], c4v[4];
#pragma unroll
    for (int j = 0; j < 4; ++j) {
        const float s = __hip_atomic_load(&ws[128 + ch + j], __ATOMIC_RELAXED, __HIP_MEMORY_SCOPE_AGENT);
        const float q = __hip_atomic_load(&ws[192 + ch + j], __ATOMIC_RELAXED, __HIP_MEMORY_SCOPE_AGENT);
        const float m = s * inv;
        const float v = q * inv - m * m;
        const float a = g2[ch + j] * rsqrtf(v + 1e-5f);
        a4[j] = a; c4v[j] = be2[ch + j] - m * a;
    }
#pragma unroll
    for (int p = 0; p < NPASS; ++p) {
        const size_t base = (size_t)(rbase + p * 4 + rg) * OUTW + 67 + ch;
        out[base + 0] = fmaxf(fmaf(ysv[p].x, a4[0], c4v[0]), 0.f);
        out[base + 1] = fmaxf(fmaf(ysv[p].y, a4[1], c4v[1]), 0.f);
        out[base + 2] = fmaxf(fmaf(ysv[p].z, a4[2], c4v[2]), 0.f);
        out[base + 3] = fmaxf(fmaf(ysv[p].w, a4[3], c4v[3]), 0.f);
    }
}

// ---------------------------------------------------------------------------
extern "C" void kernel_launch(void* const* d_in, const int* in_sizes, int n_in,
                              void* d_out, int out_size, void* d_ws, size_t ws_size,
                              hipStream_t stream)
{
    const float* cf     = (const float*)d_in[1];   // curr_feat (B,M,64)
    const float* scoord = (const float*)d_in[2];   // skip_coords (B,N,3)
    const float* sf     = (const float*)d_in[3];   // skip_feat (B,N,64)
    const int*   idxs   = (const int*)  d_in[4];   // upsampling_idxs (B,N,16)
    const float* W1     = (const float*)d_in[5];
    const float* b1     = (const float*)d_in[6];
    const float* g1     = (const float*)d_in[7];
    const float* be1    = (const float*)d_in[8];
    const float* W2     = (const float*)d_in[9];
    const float* b2     = (const float*)d_in[10];
    const float* g2     = (const float*)d_in[11];
    const float* be2    = (const float*)d_in[12];
    float* out = (float*)d_out;
    float* ws  = (float*)d_ws;

    // zero the 256 stat floats + both barrier counters
    hipMemsetAsync(ws, 0, 2048, stream);
    k_pool_proj<<<GRID_N, 256, 0, stream>>>(cf, idxs, scoord, W1, b1, g1, be1, out, ws);
    k_skip_proj<<<GRID_N, 256, 0, stream>>>(sf, W2, b2, g2, be2, out, ws);
}

// Round 4
// 286.313 us; speedup vs baseline: 8.1269x; 8.1269x over previous
//
#include <hip/hip_runtime.h>

// Problem constants (from reference setup_inputs)
#define BB 4
#define MM 16384
#define NN 32768
#define KK 16
#define ROWS (BB * NN)   // 131072
#define OUTW 131         // 3 coords + 64 + 64
#define RPW 16           // rows per wave (16 -> 2048 blocks -> 8 blocks/CU)
#define A_BLOCKS (ROWS / (RPW * 4))  // 2048

// NOTE (rounds 1-3 lesson): NO local arrays anywhere in the proj kernels.
// Runtime-indexed arrays / partially-unrolled loops demote to scratch
// (r2: 1.0 GB, r3: 2.3 GB of HBM scratch traffic). Named scalars only.

__device__ __forceinline__ float bcast(float v, int sl) {
    // wave-uniform broadcast via v_readlane
    return __int_as_float(__builtin_amdgcn_readlane(__float_as_int(v), sl));
}

// ---------------------------------------------------------------------------
// Kernel 1: gather + max-pool + (pooled @ W1 + b1) -> out[..., 3:67]
//           also writes skip_coords -> out[..., 0:3]
//           accumulates per-channel sum / sumsq into ws[0:64] / ws[64:128]
// Lane = channel. 4 rows per step, all state in named scalars.
// XCD swizzle (validated r1: FETCH 211->45 MB): block w -> XCD w&7; each
// batch owns 2 XCDs so its 4.2 MB cf slice stays L2-resident.
// ---------------------------------------------------------------------------
__global__ __launch_bounds__(256) void k_pool_proj(
    const float* __restrict__ cf, const int* __restrict__ idxs,
    const float* __restrict__ scoord,
    const float* __restrict__ W1, const float* __restrict__ b1,
    float* __restrict__ out, float* __restrict__ acc)
{
    __shared__ float lsum[64], lsq[64];
    const int lane = threadIdx.x & 63;
    const int wv   = threadIdx.x >> 6;
    if (threadIdx.x < 64) { lsum[threadIdx.x] = 0.f; lsq[threadIdx.x] = 0.f; }
    __syncthreads();

    const int w     = blockIdx.x;
    const int xcd   = w & 7;
    const int batch = xcd >> 1;                      // 2 XCDs per batch
    const int lb    = (w >> 3) + ((xcd & 1) << 8);   // [0,512) within batch
    const int rbase = batch * NN + (lb * 4 + wv) * RPW;
    const float* cfb = cf + ((size_t)batch << 20);   // batch * M * 64
    const float bias = b1[lane];

    float psum = 0.f, psq = 0.f;
    for (int s = 0; s < RPW; s += 4) {
        const int r4 = rbase + s;
        // 4 rows x 16 indices in one full-wave coalesced load
        const int mi = idxs[(size_t)r4 * KK + lane];

        float p0, p1, p2, p3;
        {   float a0 = -3.402823466e38f, a1 = a0;
#pragma unroll
            for (int k = 0; k < KK; k += 2) {
                const int m0 = __builtin_amdgcn_readlane(mi, k);
                const int m1 = __builtin_amdgcn_readlane(mi, k + 1);
                a0 = fmaxf(a0, cfb[((size_t)m0 << 6) + lane]);
                a1 = fmaxf(a1, cfb[((size_t)m1 << 6) + lane]);
            }
            p0 = fmaxf(a0, a1);
        }
        {   float a0 = -3.402823466e38f, a1 = a0;
#pragma unroll
            for (int k = 0; k < KK; k += 2) {
                const int m0 = __builtin_amdgcn_readlane(mi, 16 + k);
                const int m1 = __builtin_amdgcn_readlane(mi, 16 + k + 1);
                a0 = fmaxf(a0, cfb[((size_t)m0 << 6) + lane]);
                a1 = fmaxf(a1, cfb[((size_t)m1 << 6) + lane]);
            }
            p1 = fmaxf(a0, a1);
        }
        {   float a0 = -3.402823466e38f, a1 = a0;
#pragma unroll
            for (int k = 0; k < KK; k += 2) {
                const int m0 = __builtin_amdgcn_readlane(mi, 32 + k);
                const int m1 = __builtin_amdgcn_readlane(mi, 32 + k + 1);
                a0 = fmaxf(a0, cfb[((size_t)m0 << 6) + lane]);
                a1 = fmaxf(a1, cfb[((size_t)m1 << 6) + lane]);
            }
            p2 = fmaxf(a0, a1);
        }
        {   float a0 = -3.402823466e38f, a1 = a0;
#pragma unroll
            for (int k = 0; k < KK; k += 2) {
                const int m0 = __builtin_amdgcn_readlane(mi, 48 + k);
                const int m1 = __builtin_amdgcn_readlane(mi, 48 + k + 1);
                a0 = fmaxf(a0, cfb[((size_t)m0 << 6) + lane]);
                a1 = fmaxf(a1, cfb[((size_t)m1 << 6) + lane]);
            }
            p3 = fmaxf(a0, a1);
        }

        // y_r[lane] = b1[lane] + sum_c p_r[c] * W1[c][lane]
        // c-outer: each weight value read once per 4 rows (r0 paid 1 per row)
        float y0 = bias, y1 = bias, y2 = bias, y3 = bias;
#pragma unroll
        for (int c = 0; c < 64; ++c) {
            const float wc = W1[c * 64 + lane];
            y0 = fmaf(bcast(p0, c), wc, y0);
            y1 = fmaf(bcast(p1, c), wc, y1);
            y2 = fmaf(bcast(p2, c), wc, y2);
            y3 = fmaf(bcast(p3, c), wc, y3);
        }

        {   const size_t ob = (size_t)(r4 + 0) * OUTW;
            out[ob + 3 + lane] = y0;
            if (lane < 3) out[ob + lane] = scoord[(size_t)(r4 + 0) * 3 + lane]; }
        {   const size_t ob = (size_t)(r4 + 1) * OUTW;
            out[ob + 3 + lane] = y1;
            if (lane < 3) out[ob + lane] = scoord[(size_t)(r4 + 1) * 3 + lane]; }
        {   const size_t ob = (size_t)(r4 + 2) * OUTW;
            out[ob + 3 + lane] = y2;
            if (lane < 3) out[ob + lane] = scoord[(size_t)(r4 + 2) * 3 + lane]; }
        {   const size_t ob = (size_t)(r4 + 3) * OUTW;
            out[ob + 3 + lane] = y3;
            if (lane < 3) out[ob + lane] = scoord[(size_t)(r4 + 3) * 3 + lane]; }

        psum += (y0 + y1) + (y2 + y3);
        psq  += (y0 * y0 + y1 * y1) + (y2 * y2 + y3 * y3);
    }
    atomicAdd(&lsum[lane], psum);
    atomicAdd(&lsq[lane], psq);
    __syncthreads();
    if (threadIdx.x < 64) {
        atomicAdd(&acc[threadIdx.x],      lsum[threadIdx.x]);
        atomicAdd(&acc[64 + threadIdx.x], lsq[threadIdx.x]);
    }
}

// ---------------------------------------------------------------------------
// Kernel 2: (skip_feat @ W2 + b2) -> out[..., 67:131]
//           accumulates per-channel sum / sumsq into ws[128:192] / ws[192:256]
// Same named-scalar 4-row structure; x rows are coalesced 256B loads.
// ---------------------------------------------------------------------------
__global__ __launch_bounds__(256) void k_skip_proj(
    const float* __restrict__ sf,
    const float* __restrict__ W2, const float* __restrict__ b2,
    float* __restrict__ out, float* __restrict__ acc)
{
    __shared__ float lsum[64], lsq[64];
    const int lane = threadIdx.x & 63;
    const int wv   = threadIdx.x >> 6;
    if (threadIdx.x < 64) { lsum[threadIdx.x] = 0.f; lsq[threadIdx.x] = 0.f; }
    __syncthreads();

    const int rbase = (blockIdx.x * 4 + wv) * RPW;
    const float bias = b2[lane];

    float psum = 0.f, psq = 0.f;
    for (int s = 0; s < RPW; s += 4) {
        const int r4 = rbase + s;
        const float x0 = sf[(size_t)(r4 + 0) * 64 + lane];
        const float x1 = sf[(size_t)(r4 + 1) * 64 + lane];
        const float x2 = sf[(size_t)(r4 + 2) * 64 + lane];
        const float x3 = sf[(size_t)(r4 + 3) * 64 + lane];

        float y0 = bias, y1 = bias, y2 = bias, y3 = bias;
#pragma unroll
        for (int c = 0; c < 64; ++c) {
            const float wc = W2[c * 64 + lane];
            y0 = fmaf(bcast(x0, c), wc, y0);
            y1 = fmaf(bcast(x1, c), wc, y1);
            y2 = fmaf(bcast(x2, c), wc, y2);
            y3 = fmaf(bcast(x3, c), wc, y3);
        }

        out[(size_t)(r4 + 0) * OUTW + 67 + lane] = y0;
        out[(size_t)(r4 + 1) * OUTW + 67 + lane] = y1;
        out[(size_t)(r4 + 2) * OUTW + 67 + lane] = y2;
        out[(size_t)(r4 + 3) * OUTW + 67 + lane] = y3;

        psum += (y0 + y1) + (y2 + y3);
        psq  += (y0 * y0 + y1 * y1) + (y2 * y2 + y3 * y3);
    }
    atomicAdd(&lsum[lane], psum);
    atomicAdd(&lsq[lane], psq);
    __syncthreads();
    if (threadIdx.x < 64) {
        atomicAdd(&acc[128 + threadIdx.x], lsum[threadIdx.x]);
        atomicAdd(&acc[192 + threadIdx.x], lsq[threadIdx.x]);
    }
}

// ---------------------------------------------------------------------------
// Kernel 3: fold sums -> affine params  a = g*rsqrt(var+eps), c = beta - mu*a
// ws layout: [0:64] sum1 [64:128] sq1 [128:192] sum2 [192:256] sq2
//            [256:384] a (a1|a2)  [384:512] c (c1|c2)
// ---------------------------------------------------------------------------
__global__ void k_stats(float* __restrict__ ws,
                        const float* __restrict__ g1, const float* __restrict__ be1,
                        const float* __restrict__ g2, const float* __restrict__ be2)
{
    const int o = threadIdx.x;  // 64 threads
    const float inv = 1.0f / (float)ROWS;
    float m1 = ws[o] * inv;
    float v1 = ws[64 + o] * inv - m1 * m1;
    float a1 = g1[o] * rsqrtf(v1 + 1e-5f);
    ws[256 + o] = a1;
    ws[384 + o] = be1[o] - m1 * a1;
    float m2 = ws[128 + o] * inv;
    float v2 = ws[192 + o] * inv - m2 * m2;
    float a2 = g2[o] * rsqrtf(v2 + 1e-5f);
    ws[256 + 64 + o] = a2;
    ws[384 + 64 + o] = be2[o] - m2 * a2;
}

// ---------------------------------------------------------------------------
// Kernel 4: in-place  out[r*131 + 3 + j] = relu(a[j]*y + c[j]),  j in [0,128)
// ---------------------------------------------------------------------------
__global__ __launch_bounds__(256) void k_finalize(float* __restrict__ out,
                                                  const float* __restrict__ ws)
{
    const size_t T  = (size_t)gridDim.x * blockDim.x;
    const size_t t0 = (size_t)blockIdx.x * blockDim.x + threadIdx.x;
#pragma unroll
    for (int i = 0; i < 4; ++i) {
        const size_t e = t0 + (size_t)i * T;       // e < ROWS*128
        const size_t r = e >> 7;
        const int    j = (int)(e & 127);
        const size_t ad = r * OUTW + 3 + j;
        const float v = out[ad];
        out[ad] = fmaxf(fmaf(v, ws[256 + j], ws[384 + j]), 0.f);
    }
}

// ---------------------------------------------------------------------------
extern "C" void kernel_launch(void* const* d_in, const int* in_sizes, int n_in,
                              void* d_out, int out_size, void* d_ws, size_t ws_size,
                              hipStream_t stream)
{
    const float* cf     = (const float*)d_in[1];   // curr_feat (B,M,64)
    const float* scoord = (const float*)d_in[2];   // skip_coords (B,N,3)
    const float* sf     = (const float*)d_in[3];   // skip_feat (B,N,64)
    const int*   idxs   = (const int*)  d_in[4];   // upsampling_idxs (B,N,16)
    const float* W1     = (const float*)d_in[5];
    const float* b1     = (const float*)d_in[6];
    const float* g1     = (const float*)d_in[7];
    const float* be1    = (const float*)d_in[8];
    const float* W2     = (const float*)d_in[9];
    const float* b2     = (const float*)d_in[10];
    const float* g2     = (const float*)d_in[11];
    const float* be2    = (const float*)d_in[12];
    float* out = (float*)d_out;
    float* ws  = (float*)d_ws;

    hipMemsetAsync(ws, 0, 256 * sizeof(float), stream);  // zero the accumulators
    k_pool_proj<<<A_BLOCKS, 256, 0, stream>>>(cf, idxs, scoord, W1, b1, out, ws);
    k_skip_proj<<<A_BLOCKS, 256, 0, stream>>>(sf, W2, b2, out, ws);
    k_stats<<<1, 64, 0, stream>>>(ws, g1, be1, g2, be2);
    // ROWS*128 = 16,777,216 elements; 16384 blocks * 256 threads * 4 elems
    k_finalize<<<16384, 256, 0, stream>>>(out, ws);
}